// Round 6
// baseline (216.549 us; speedup 1.0000x reference)
//
#include <hip/hip_runtime.h>

namespace {

constexpr int N_ = 512;
constexpr int M_ = 300;   // MEM
constexpr int H_ = 64;    // HID
constexpr float SLOPE_ = 0.01f;

// ---- workspace layout (float offsets). No atomics; every buffer fully
// written by plain stores before read. ----
constexpr long OFF_CW1AI = 0;                    // 300 x 64  (w1 @ Ai)
constexpr long OFF_CW1AJ = OFF_CW1AI + 19200;    // 300 x 64  (w1 @ Aj)
constexpr long OFF_BS1I  = OFF_CW1AJ + 19200;    // 64        (b1 @ Ai)
constexpr long OFF_BS1J  = OFF_BS1I  + 64;       // 64        (b1 @ Aj + a1b)
constexpr long OFF_H0    = OFF_BS1J  + 64;       // 1024 x 300
constexpr long OFF_F1    = OFF_H0    + 307200;   // 1024 x 300
constexpr long OFF_H1    = OFF_F1    + 307200;   // 1024 x 300
constexpr long OFF_ZP0   = OFF_H1    + 307200;   // 2 x 256 softmax partials
constexpr long OFF_ZP1   = OFF_ZP0   + 512;
constexpr long OFF_P0    = OFF_ZP1   + 512;      // 2 x 512 x 512
constexpr long OFF_P1    = OFF_P0    + 524288;   // total ~7 MB

// ---------------------------------------------------------------------------
// 64x64 GEMM tile, 256 threads, 4x4 micro (one ds_read_b128 per fragment),
// XOR-swizzled k-major A staging (validated in round 5, TPB=256 path):
//   C = scale * A @ W + bias,  scale = Zp ? 1/sum(Zp[0..255]) : 1
// smem: As 32x68 | Ws 32x68 | zred (4356 floats used).
// ---------------------------------------------------------------------------
__device__ __forceinline__ void gemm_tile64(
    const float* __restrict__ A, const float* __restrict__ W,
    const float* __restrict__ bias, const float* __restrict__ Zp,
    float* __restrict__ C, int K, int lda, int Cc, int R, int local,
    float* smem)
{
    float (*As)[68] = (float(*)[68])smem;
    float (*Ws)[68] = (float(*)[68])(smem + 2176);
    float* zred = smem + 4352;

    const int tx   = (Cc + 63) >> 6;
    const int row0 = (local / tx) * 64;
    const int col0 = (local % tx) * 64;

    const int t  = threadIdx.x;
    const int ar = t >> 2, aq = t & 3;           // A: row 0..63, 8 k/thread
    const int arow = min(row0 + ar, R - 1);
    const int wr = t >> 3, wq = t & 7;           // W: k-row 0..31, 8 c/thread
    const int tr = t >> 4, tc = t & 15;          // micro-tile coords

    float4 av[2], wv[2];
    auto loadA = [&](int k0) {
        #pragma unroll
        for (int f = 0; f < 2; ++f) {
            const int k = k0 + aq * 8 + f * 4;
            float4 r = make_float4(0.f, 0.f, 0.f, 0.f);
            if (k + 3 < K) {
                r = *(const float4*)(A + (long)arow * lda + k);
            } else {
                #pragma unroll
                for (int u = 0; u < 4; ++u)
                    if (k + u < K) (&r.x)[u] = A[(long)arow * lda + k + u];
            }
            av[f] = r;
        }
    };
    auto loadW = [&](int k0) {
        const int gk = k0 + wr;
        #pragma unroll
        for (int f = 0; f < 2; ++f) {
            const int c = col0 + wq * 8 + f * 4;
            float4 r = make_float4(0.f, 0.f, 0.f, 0.f);
            if (gk < K) {
                if (c + 3 < Cc) {
                    r = *(const float4*)(W + (long)gk * Cc + c);
                } else {
                    #pragma unroll
                    for (int u = 0; u < 4; ++u)
                        if (c + u < Cc) (&r.x)[u] = W[(long)gk * Cc + c + u];
                }
            }
            wv[f] = r;
        }
    };

    float acc[4][4] = {};
    loadA(0);
    loadW(0);

    for (int k0 = 0; k0 < K; k0 += 32) {
        #pragma unroll
        for (int f = 0; f < 2; ++f)
            #pragma unroll
            for (int c = 0; c < 4; ++c) {
                const int kk = aq * 8 + f * 4 + c;
                const int s  = (kk >> 3) & 3;
                As[kk][ar ^ (s << 2)] = (&av[f].x)[c];
            }
        #pragma unroll
        for (int f = 0; f < 2; ++f)
            *(float4*)&Ws[wr][wq * 8 + 4 * f] = wv[f];
        __syncthreads();

        if (k0 + 32 < K) { loadA(k0 + 32); loadW(k0 + 32); }

        #pragma unroll
        for (int k = 0; k < 32; ++k) {
            const int s = (k >> 3) & 3;
            const float4 a4 = *(const float4*)&As[k][(tr ^ s) * 4];
            const float4 w4 = *(const float4*)&Ws[k][tc * 4];
            const float a_[4] = {a4.x, a4.y, a4.z, a4.w};
            #pragma unroll
            for (int i = 0; i < 4; ++i) {
                acc[i][0] = fmaf(a_[i], w4.x, acc[i][0]);
                acc[i][1] = fmaf(a_[i], w4.y, acc[i][1]);
                acc[i][2] = fmaf(a_[i], w4.z, acc[i][2]);
                acc[i][3] = fmaf(a_[i], w4.w, acc[i][3]);
            }
        }
        __syncthreads();
    }

    float scale = 1.0f;
    if (Zp != nullptr) {                   // softmax denom (256 partials)
        float v = Zp[t];
        #pragma unroll
        for (int off = 32; off > 0; off >>= 1)
            v += __shfl_down(v, off, 64);
        if ((t & 63) == 0) zred[t >> 6] = v;
        __syncthreads();
        scale = 1.0f / (zred[0] + zred[1] + zred[2] + zred[3]);
    }

    const int cbase = col0 + tc * 4;
    float bv[4] = {0.f, 0.f, 0.f, 0.f};
    if (bias != nullptr) {
        #pragma unroll
        for (int u = 0; u < 4; ++u)
            if (cbase + u < Cc) bv[u] = bias[cbase + u];
    }
    #pragma unroll
    for (int i = 0; i < 4; ++i) {
        const int r = row0 + tr * 4 + i;
        if (r < R) {
            if (cbase + 3 < Cc) {
                float4 o;
                o.x = fmaf(acc[i][0], scale, bv[0]);
                o.y = fmaf(acc[i][1], scale, bv[1]);
                o.z = fmaf(acc[i][2], scale, bv[2]);
                o.w = fmaf(acc[i][3], scale, bv[3]);
                *(float4*)(C + (long)r * Cc + cbase) = o;
            } else {
                #pragma unroll
                for (int u = 0; u < 4; ++u)
                    if (cbase + u < Cc)
                        C[(long)r * Cc + cbase + u] = fmaf(acc[i][u], scale, bv[u]);
            }
        }
    }
}

struct JobsK {
    const float* A[5]; const float* W[5]; const float* bias[5];
    const float* Zp[5]; float* C[5];
    int K[5]; int lda[5]; int Cc[5]; int R[5];
    int off[5]; int njobs;
};

__global__ __launch_bounds__(256)
void gemm_jobs(JobsK jb)
{
    __shared__ __align__(16) float smem[4360];
    const int bid = blockIdx.x;
    int j = jb.njobs - 1;
    while (j > 0 && bid < jb.off[j]) --j;
    gemm_tile64(jb.A[j], jb.W[j], jb.bias[j], jb.Zp[j], jb.C[j],
                jb.K[j], jb.lda[j], jb.Cc[j], jb.R[j], bid - jb.off[j], smem);
}

// ---------------------------------------------------------------------------
// Fused attention: blocks 0..511 compute one (b, 32i x 32j) tile of
// p = adj*exp(leaky(e)) + Zpart, with si/sj tiles computed ON THE FLY from h
// (mini-GEMMs K=300 against Wi/Wj), eliminating the standalone s-GEMM
// dispatches. Blocks >= 512 run an appended 64x64 GEMM job (h1 = f1@w1+b1),
// which shares the dispatch since both depend only on f1.
//   si = h@Wi (+bi),  sj = h@Wj (+bj)   [bj includes a1b]
// smem phases: {Hi 32x36 | Hj 32x36 | WAi 32x68 | WAj 32x68} (6656 floats)
//           -> {Si 32x68 | Sj 32x68} (union; sync-separated).
// ---------------------------------------------------------------------------
__global__ __launch_bounds__(256)
void attn_plus(const float* __restrict__ h, const float* __restrict__ Wi,
               const float* __restrict__ Wj, const float* __restrict__ bi,
               const float* __restrict__ bj, const float* __restrict__ adj,
               const float* __restrict__ a2w, const float* __restrict__ a2b,
               float* __restrict__ p, float* __restrict__ Zpart,
               const float* gA, const float* gW, const float* gbias,
               float* gC, int gK, int glda, int gCc, int gR)
{
    __shared__ __align__(16) float smem[6656];
    __shared__ float red[4];

    const int bid = blockIdx.x;
    if (bid >= 512) {    // appended GEMM tiles (D4: h1 = f1@w1 + b1)
        gemm_tile64(gA, gW, gbias, nullptr, gC, gK, glda, gCc, gR,
                    bid - 512, smem);
        return;
    }

    float* Hi  = smem;           // [32][36]
    float* Hj  = smem + 1152;    // [32][36]
    float* WAi = smem + 2304;    // [32][68]
    float* WAj = smem + 4480;    // [32][68]

    const int b    = bid >> 8;
    const int tile = bid & 255;
    const int i0 = (tile >> 4) * 32;
    const int j0 = (tile & 15) * 32;
    const int t  = threadIdx.x;

    const int tm0 = (t >> 4) * 2;        // mini-gemm micro: 2 rows x 4 cols
    const int tn0 = (t & 15) * 4;
    const int hr  = t >> 3;              // staging row 0..31
    const int hk  = (t & 7) * 4;         // Hi/Hj col
    const int wc0 = (t & 7) * 8;         // WAi/WAj cols (two float4)

    float acci[2][4] = {}, accj[2][4] = {};

    for (int k0 = 0; k0 < M_; k0 += 32) {
        {   // stage h i-rows / j-rows (32x32) and Wi/Wj slabs (32x64)
            const int k = k0 + hk;
            float4 hi4 = make_float4(0.f, 0.f, 0.f, 0.f), hj4 = hi4;
            if (k + 3 < M_) {            // M_ % 4 == 0: vec or fully OOB
                hi4 = *(const float4*)(h + ((long)(b * N_ + i0 + hr)) * M_ + k);
                hj4 = *(const float4*)(h + ((long)(b * N_ + j0 + hr)) * M_ + k);
            }
            *(float4*)&Hi[hr * 36 + hk] = hi4;
            *(float4*)&Hj[hr * 36 + hk] = hj4;

            const int wrow = k0 + hr;
            float4 wi0 = make_float4(0.f, 0.f, 0.f, 0.f);
            float4 wi1 = wi0, wj0 = wi0, wj1 = wi0;
            if (wrow < M_) {
                wi0 = *(const float4*)(Wi + (long)wrow * H_ + wc0);
                wi1 = *(const float4*)(Wi + (long)wrow * H_ + wc0 + 4);
                wj0 = *(const float4*)(Wj + (long)wrow * H_ + wc0);
                wj1 = *(const float4*)(Wj + (long)wrow * H_ + wc0 + 4);
            }
            *(float4*)&WAi[hr * 68 + wc0]     = wi0;
            *(float4*)&WAi[hr * 68 + wc0 + 4] = wi1;
            *(float4*)&WAj[hr * 68 + wc0]     = wj0;
            *(float4*)&WAj[hr * 68 + wc0 + 4] = wj1;
        }
        __syncthreads();

        #pragma unroll
        for (int k = 0; k < 32; ++k) {
            const float ai0 = Hi[tm0 * 36 + k];
            const float ai1 = Hi[(tm0 + 1) * 36 + k];
            const float aj0 = Hj[tm0 * 36 + k];
            const float aj1 = Hj[(tm0 + 1) * 36 + k];
            const float4 wi = *(const float4*)&WAi[k * 68 + tn0];
            const float4 wj = *(const float4*)&WAj[k * 68 + tn0];
            acci[0][0] = fmaf(ai0, wi.x, acci[0][0]);
            acci[0][1] = fmaf(ai0, wi.y, acci[0][1]);
            acci[0][2] = fmaf(ai0, wi.z, acci[0][2]);
            acci[0][3] = fmaf(ai0, wi.w, acci[0][3]);
            acci[1][0] = fmaf(ai1, wi.x, acci[1][0]);
            acci[1][1] = fmaf(ai1, wi.y, acci[1][1]);
            acci[1][2] = fmaf(ai1, wi.z, acci[1][2]);
            acci[1][3] = fmaf(ai1, wi.w, acci[1][3]);
            accj[0][0] = fmaf(aj0, wj.x, accj[0][0]);
            accj[0][1] = fmaf(aj0, wj.y, accj[0][1]);
            accj[0][2] = fmaf(aj0, wj.z, accj[0][2]);
            accj[0][3] = fmaf(aj0, wj.w, accj[0][3]);
            accj[1][0] = fmaf(aj1, wj.x, accj[1][0]);
            accj[1][1] = fmaf(aj1, wj.y, accj[1][1]);
            accj[1][2] = fmaf(aj1, wj.z, accj[1][2]);
            accj[1][3] = fmaf(aj1, wj.w, accj[1][3]);
        }
        __syncthreads();
    }

    // ---- publish s-tiles into LDS (union over staging space) ----
    float biv[4] = {0.f, 0.f, 0.f, 0.f};
    float bjv[4];
    if (bi != nullptr) {
        #pragma unroll
        for (int u = 0; u < 4; ++u) biv[u] = bi[tn0 + u];
    }
    #pragma unroll
    for (int u = 0; u < 4; ++u) bjv[u] = bj[tn0 + u];

    float* Si = smem;            // [32][68]
    float* Sj = smem + 2176;     // [32][68]
    #pragma unroll
    for (int ii = 0; ii < 2; ++ii)
        #pragma unroll
        for (int u = 0; u < 4; ++u) {
            Si[(tm0 + ii) * 68 + tn0 + u] = acci[ii][u] + biv[u];
            Sj[(tm0 + ii) * 68 + tn0 + u] = accj[ii][u] + bjv[u];
        }
    __syncthreads();

    // ---- e -> p -> Zpart (proven round-3 structure) ----
    const int i  = t >> 3;
    const int jl = t & 7;

    float e[4] = {0.f, 0.f, 0.f, 0.f};
    #pragma unroll
    for (int hh = 0; hh < H_; hh += 4) {
        const float4 a4 = *(const float4*)&Si[i * 68 + hh];
        const float w0v = a2w[hh + 0];
        const float w1v = a2w[hh + 1];
        const float w2v = a2w[hh + 2];
        const float w3v = a2w[hh + 3];
        #pragma unroll
        for (int u = 0; u < 4; ++u) {
            const float4 b4 = *(const float4*)&Sj[(jl + 8 * u) * 68 + hh];
            e[u] = fmaf(fmaxf(a4.x + b4.x, 0.f), w0v, e[u]);
            e[u] = fmaf(fmaxf(a4.y + b4.y, 0.f), w1v, e[u]);
            e[u] = fmaf(fmaxf(a4.z + b4.z, 0.f), w2v, e[u]);
            e[u] = fmaf(fmaxf(a4.w + b4.w, 0.f), w3v, e[u]);
        }
    }

    const float a2bv = a2b[0];
    const long rowbase = ((long)(b * N_ + i0 + i)) * N_ + j0 + jl;
    float lsum = 0.f;
    #pragma unroll
    for (int u = 0; u < 4; ++u) {
        float ev = e[u] + a2bv;
        ev = (ev >= 0.f) ? ev : SLOPE_ * ev;
        const float m  = adj[rowbase + 8 * u];
        const float pv = m * __expf(ev);
        p[rowbase + 8 * u] = pv;
        lsum += pv;
    }

    #pragma unroll
    for (int off = 32; off > 0; off >>= 1)
        lsum += __shfl_down(lsum, off, 64);
    if ((t & 63) == 0) red[t >> 6] = lsum;
    __syncthreads();
    if (t == 0)
        Zpart[b * 256 + tile] = red[0] + red[1] + red[2] + red[3];
}

} // namespace

extern "C" void kernel_launch(void* const* d_in, const int* in_sizes, int n_in,
                              void* d_out, int out_size, void* d_ws, size_t ws_size,
                              hipStream_t stream)
{
    (void)in_sizes; (void)n_in; (void)out_size; (void)ws_size;
    const float* feature = (const float*)d_in[0];
    const float* adj     = (const float*)d_in[1];
    const float* w0      = (const float*)d_in[2];
    const float* b0      = (const float*)d_in[3];
    const float* w1      = (const float*)d_in[4];
    const float* b1      = (const float*)d_in[5];
    const float* a1w     = (const float*)d_in[6];   // (600, 64) row-major
    const float* a1b     = (const float*)d_in[7];
    const float* a2w     = (const float*)d_in[8];
    const float* a2b     = (const float*)d_in[9];
    float* out = (float*)d_out;
    float* ws  = (float*)d_ws;

    float* cW1Ai = ws + OFF_CW1AI;
    float* cW1Aj = ws + OFF_CW1AJ;
    float* bs1i  = ws + OFF_BS1I;
    float* bs1j  = ws + OFF_BS1J;
    float* h0    = ws + OFF_H0;
    float* f1    = ws + OFF_F1;
    float* h1    = ws + OFF_H1;
    float* Zp0   = ws + OFF_ZP0;
    float* Zp1   = ws + OFF_ZP1;
    float* p0    = ws + OFF_P0;
    float* p1    = ws + OFF_P1;

    const float* Ai = a1w;                    // top half (300 x 64)
    const float* Aj = a1w + (long)M_ * H_;    // bottom half

    auto set_job = [](JobsK& jb, int j, const float* A, const float* W,
                      const float* bias, const float* Zp, float* C,
                      int K, int lda, int Cc, int R, int& tiles) {
        jb.A[j] = A; jb.W[j] = W; jb.bias[j] = bias; jb.Zp[j] = Zp; jb.C[j] = C;
        jb.K[j] = K; jb.lda[j] = lda; jb.Cc[j] = Cc; jb.R[j] = R;
        jb.off[j] = tiles;
        tiles += ((R + 63) / 64) * ((Cc + 63) / 64);
    };

    // ---- D1: h0 = feature@w0+b0 | layer-1 fused weights (92 blocks) ----
    {
        JobsK jb; int tiles = 0;
        set_job(jb, 0, feature, w0, b0,   nullptr, h0,    512, 512, M_, 1024, tiles);
        set_job(jb, 1, w1, Ai, nullptr, nullptr, cW1Ai, M_, M_, H_, M_, tiles);
        set_job(jb, 2, w1, Aj, nullptr, nullptr, cW1Aj, M_, M_, H_, M_, tiles);
        set_job(jb, 3, b1, Ai, nullptr, nullptr, bs1i,  M_, M_, H_, 1,  tiles);
        set_job(jb, 4, b1, Aj, a1b,     nullptr, bs1j,  M_, M_, H_, 1,  tiles);
        jb.njobs = 5;
        gemm_jobs<<<dim3(tiles), dim3(256), 0, stream>>>(jb);
    }

    // ---- D2: attn0 (si/sj on the fly from h0) -> p0, Zp0 (512 blocks) ----
    attn_plus<<<dim3(512), dim3(256), 0, stream>>>(
        h0, Ai, Aj, nullptr, a1b, adj, a2w, a2b, p0, Zp0,
        nullptr, nullptr, nullptr, nullptr, 0, 0, 0, 0);

    // ---- D3: f1 = (1/Z0) * p0@h0 (80 blocks) ----
    {
        JobsK jb; int tiles = 0;
        set_job(jb, 0, p0,          h0,              nullptr, Zp0,       f1,
                512, 512, M_, 512, tiles);
        set_job(jb, 1, p0 + 262144, h0 + (long)N_*M_, nullptr, Zp0 + 256,
                f1 + (long)N_*M_, 512, 512, M_, 512, tiles);
        jb.njobs = 2;
        gemm_jobs<<<dim3(tiles), dim3(256), 0, stream>>>(jb);
    }

    // ---- D4: attn1 (s1 from f1 via cW1) -> p1, Zp1 | h1 = f1@w1+b1 ----
    attn_plus<<<dim3(512 + 80), dim3(256), 0, stream>>>(
        f1, cW1Ai, cW1Aj, bs1i, bs1j, adj, a2w, a2b, p1, Zp1,
        f1, w1, b1, h1, M_, M_, M_, 1024);

    // ---- D5: out = (1/Z1) * p1@h1 (80 blocks) ----
    {
        JobsK jb; int tiles = 0;
        set_job(jb, 0, p1,          h1,              nullptr, Zp1,       out,
                512, 512, M_, 512, tiles);
        set_job(jb, 1, p1 + 262144, h1 + (long)N_*M_, nullptr, Zp1 + 256,
                out + (long)N_*M_, 512, 512, M_, 512, tiles);
        jb.njobs = 2;
        gemm_jobs<<<dim3(tiles), dim3(256), 0, stream>>>(jb);
    }
}

// Round 7
// 177.963 us; speedup vs baseline: 1.2168x; 1.2168x over previous
//
#include <hip/hip_runtime.h>

namespace {

constexpr int N_ = 512;
constexpr int M_ = 300;   // MEM
constexpr int H_ = 64;    // HID
constexpr float SLOPE_ = 0.01f;

// ---- workspace layout (float offsets). No atomics; every buffer fully
// written by plain stores before read. Split-K slices are separate buffers
// folded by consumers (A-side, W-side, or attn staging). ----
constexpr long OFF_CW1AI = 0;                        // 300 x 64
constexpr long OFF_CW1AJ = OFF_CW1AI + 19200;
constexpr long OFF_BS1I  = OFF_CW1AJ + 19200;        // 64
constexpr long OFF_BS1J  = OFF_BS1I  + 64;
constexpr long OFF_H0S   = OFF_BS1J  + 64;           // 3 x (1024 x 300)
constexpr long OFF_SI0S  = OFF_H0S   + 3L * 307200;  // 4 x (1024 x 64)
constexpr long OFF_SJ0S  = OFF_SI0S  + 4L * 65536;
constexpr long OFF_F1S   = OFF_SJ0S  + 4L * 65536;   // 4 x (1024 x 300)
constexpr long OFF_H1S   = OFF_F1S   + 4L * 307200;  // 2 x (1024 x 300)
constexpr long OFF_SI1S  = OFF_H1S   + 2L * 307200;  // 2 x (1024 x 64)
constexpr long OFF_SJ1S  = OFF_SI1S  + 2L * 65536;
constexpr long OFF_ZP0   = OFF_SJ1S  + 2L * 65536;   // 2 x 256
constexpr long OFF_ZP1   = OFF_ZP0   + 512;
constexpr long OFF_P0    = OFF_ZP1   + 512;          // 2 x 512 x 512
constexpr long OFF_P1    = OFF_P0    + 524288;
constexpr long OFF_OUTS  = OFF_P1    + 524288;       // 4 x (1024 x 300)
// total ~5.9M floats ~23.5 MB

__device__ __forceinline__ float4 f4add(float4 a, float4 b) {
    a.x += b.x; a.y += b.y; a.z += b.z; a.w += b.w; return a;
}

// ---------------------------------------------------------------------------
// Multi-job GEMM, 64x64 tile, 256 threads, 4x4 micro: one ds_read_b128 per
// fragment (1.5 LDS-cyc per 16 wave-FMA). XOR-swizzled k-major A staging
// (correctness proven in rounds 5/6).
//   C[slice] = scale * (sum_s A[s]) @ (sum_s W[s]) + (slice==0 ? bias : 0)
// split>1: K sliced in whole 32-slabs; each slice writes its OWN buffer
// (C + slice*cslice) with plain stores — no atomics.
// ---------------------------------------------------------------------------
struct JobsK {
    const float* A[5]; long afs[5];
    const float* W[5]; long wfs[5];
    const float* bias[5]; const float* Zp[5];
    float* C[5]; long cslice[5];
    int K[5]; int lda[5]; int Cc[5]; int R[5]; int split[5];
    int off[5]; int njobs;
};

template<int AFOLD, int WFOLD>
__global__ __launch_bounds__(256)
void gemm_jobs(JobsK jb)
{
    __shared__ __align__(16) float As[32][68];
    __shared__ __align__(16) float Ws[32][68];
    __shared__ float zred[4];

    const int bid = blockIdx.x;
    int j = jb.njobs - 1;
    while (j > 0 && bid < jb.off[j]) --j;
    const int local = bid - jb.off[j];

    const float* __restrict__ A = jb.A[j];  const long afs = jb.afs[j];
    const float* __restrict__ W = jb.W[j];  const long wfs = jb.wfs[j];
    const float* bias = jb.bias[j];
    const float* Zp   = jb.Zp[j];
    float* __restrict__ C = jb.C[j];
    const int K = jb.K[j], lda = jb.lda[j], Cc = jb.Cc[j], R = jb.R[j];
    const int split = jb.split[j];

    const int tx  = (Cc + 63) >> 6;
    const int ty  = (R + 63) >> 6;
    const int nrc = tx * ty;
    const int tile  = local % nrc;
    const int slice = local / nrc;
    const int row0 = (tile / tx) * 64;
    const int col0 = (tile % tx) * 64;
    const int nslab = (K + 31) >> 5;
    const int spl   = (nslab + split - 1) / split;
    const int kb    = slice * spl * 32;
    const int Ke    = min(K, kb + spl * 32);
    C += (long)slice * jb.cslice[j];

    const int t  = threadIdx.x;
    const int ar = t >> 2, aq = t & 3;           // A: row 0..63, 8 k/thread
    const int arow = min(row0 + ar, R - 1);
    const int wr = t >> 3, wq = t & 7;           // W: k-row 0..31, 8 c/thread
    const int tr = t >> 4, tc = t & 15;          // micro-tile coords

    float4 av[2], wv[2];
    auto loadA = [&](int k0) {
        #pragma unroll
        for (int f = 0; f < 2; ++f) {
            const int k = k0 + aq * 8 + f * 4;
            const long base = (long)arow * lda + k;
            float4 r = make_float4(0.f, 0.f, 0.f, 0.f);
            if (k + 3 < Ke) {
                #pragma unroll
                for (int s = 0; s < AFOLD; ++s)
                    r = f4add(r, *(const float4*)(A + (long)s * afs + base));
            } else {
                #pragma unroll
                for (int u = 0; u < 4; ++u)
                    if (k + u < Ke) {
                        float v = 0.f;
                        #pragma unroll
                        for (int s = 0; s < AFOLD; ++s)
                            v += A[(long)s * afs + base + u];
                        (&r.x)[u] = v;
                    }
            }
            av[f] = r;
        }
    };
    auto loadW = [&](int k0) {
        const int gk = k0 + wr;
        #pragma unroll
        for (int f = 0; f < 2; ++f) {
            const int c = col0 + wq * 8 + f * 4;
            float4 r = make_float4(0.f, 0.f, 0.f, 0.f);
            if (gk < Ke) {
                const long base = (long)gk * Cc + c;
                if (c + 3 < Cc) {
                    #pragma unroll
                    for (int s = 0; s < WFOLD; ++s)
                        r = f4add(r, *(const float4*)(W + (long)s * wfs + base));
                } else {
                    #pragma unroll
                    for (int u = 0; u < 4; ++u)
                        if (c + u < Cc) {
                            float v = 0.f;
                            #pragma unroll
                            for (int s = 0; s < WFOLD; ++s)
                                v += W[(long)s * wfs + base + u];
                            (&r.x)[u] = v;
                        }
                }
            }
            wv[f] = r;
        }
    };

    float acc[4][4] = {};
    loadA(kb);
    loadW(kb);

    for (int k0 = kb; k0 < Ke; k0 += 32) {
        #pragma unroll
        for (int f = 0; f < 2; ++f)
            #pragma unroll
            for (int c = 0; c < 4; ++c) {
                const int kk = aq * 8 + f * 4 + c;
                const int s  = (kk >> 3) & 3;
                As[kk][ar ^ (s << 2)] = (&av[f].x)[c];
            }
        #pragma unroll
        for (int f = 0; f < 2; ++f)
            *(float4*)&Ws[wr][wq * 8 + 4 * f] = wv[f];
        __syncthreads();

        if (k0 + 32 < Ke) { loadA(k0 + 32); loadW(k0 + 32); }

        #pragma unroll
        for (int k = 0; k < 32; ++k) {
            const int s = (k >> 3) & 3;
            const float4 a4 = *(const float4*)&As[k][(tr ^ s) * 4];
            const float4 w4 = *(const float4*)&Ws[k][tc * 4];
            const float a_[4] = {a4.x, a4.y, a4.z, a4.w};
            #pragma unroll
            for (int i = 0; i < 4; ++i) {
                acc[i][0] = fmaf(a_[i], w4.x, acc[i][0]);
                acc[i][1] = fmaf(a_[i], w4.y, acc[i][1]);
                acc[i][2] = fmaf(a_[i], w4.z, acc[i][2]);
                acc[i][3] = fmaf(a_[i], w4.w, acc[i][3]);
            }
        }
        __syncthreads();
    }

    float scale = 1.0f;
    if (Zp != nullptr) {                   // softmax denom (256 partials)
        float v = Zp[t];
        #pragma unroll
        for (int off = 32; off > 0; off >>= 1)
            v += __shfl_down(v, off, 64);
        if ((t & 63) == 0) zred[t >> 6] = v;
        __syncthreads();
        scale = 1.0f / (zred[0] + zred[1] + zred[2] + zred[3]);
    }

    const int cbase = col0 + tc * 4;
    float bv[4] = {0.f, 0.f, 0.f, 0.f};
    if (bias != nullptr && slice == 0) {
        #pragma unroll
        for (int u = 0; u < 4; ++u)
            if (cbase + u < Cc) bv[u] = bias[cbase + u];
    }
    #pragma unroll
    for (int i = 0; i < 4; ++i) {
        const int r = row0 + tr * 4 + i;
        if (r < R) {
            if (cbase + 3 < Cc) {
                float4 o;
                o.x = fmaf(acc[i][0], scale, bv[0]);
                o.y = fmaf(acc[i][1], scale, bv[1]);
                o.z = fmaf(acc[i][2], scale, bv[2]);
                o.w = fmaf(acc[i][3], scale, bv[3]);
                *(float4*)(C + (long)r * Cc + cbase) = o;
            } else {
                #pragma unroll
                for (int u = 0; u < 4; ++u)
                    if (cbase + u < Cc)
                        C[(long)r * Cc + cbase + u] = fmaf(acc[i][u], scale, bv[u]);
            }
        }
    }
}

// ---------------------------------------------------------------------------
// Attention numerator tile (32i x 32j), FOLD si/sj slices (stride 65536)
// summed at staging. Proven in rounds 3/5.
// ---------------------------------------------------------------------------
template<int FOLD>
__global__ __launch_bounds__(256)
void attn_k(const float* __restrict__ si, const float* __restrict__ sj,
            const float* __restrict__ adj, const float* __restrict__ a2w,
            const float* __restrict__ a2b, float* __restrict__ p,
            float* __restrict__ Zpart)
{
    __shared__ __align__(16) float Si[32][68];
    __shared__ __align__(16) float Sj[32][68];
    __shared__ float red[4];

    const int g    = blockIdx.x;          // 512 = 2b x 16it x 16jt
    const int b    = g >> 8;
    const int tile = g & 255;
    const int i0 = (tile >> 4) * 32;
    const int j0 = (tile & 15) * 32;
    const int t  = threadIdx.x;

    {   // stage 32x64 tiles (summing FOLD slices)
        const int r  = t >> 3;
        const int hc = (t & 7) * 8;
        const long gib = ((long)(b * N_ + i0 + r)) * H_ + hc;
        const long gjb = ((long)(b * N_ + j0 + r)) * H_ + hc;
        float4 a0 = make_float4(0.f, 0.f, 0.f, 0.f);
        float4 a1 = a0, b0v = a0, b1v = a0;
        #pragma unroll
        for (int s = 0; s < FOLD; ++s) {
            const float* gi = si + (long)s * 65536 + gib;
            const float* gj = sj + (long)s * 65536 + gjb;
            a0  = f4add(a0,  *(const float4*)(gi));
            a1  = f4add(a1,  *(const float4*)(gi + 4));
            b0v = f4add(b0v, *(const float4*)(gj));
            b1v = f4add(b1v, *(const float4*)(gj + 4));
        }
        *(float4*)&Si[r][hc]     = a0;
        *(float4*)&Si[r][hc + 4] = a1;
        *(float4*)&Sj[r][hc]     = b0v;
        *(float4*)&Sj[r][hc + 4] = b1v;
    }
    __syncthreads();

    const int i  = t >> 3;
    const int jl = t & 7;

    float e[4] = {0.f, 0.f, 0.f, 0.f};
    #pragma unroll
    for (int h0 = 0; h0 < H_; h0 += 4) {
        const float4 a4 = *(const float4*)&Si[i][h0];
        const float w0v = a2w[h0 + 0];
        const float w1v = a2w[h0 + 1];
        const float w2v = a2w[h0 + 2];
        const float w3v = a2w[h0 + 3];
        #pragma unroll
        for (int u = 0; u < 4; ++u) {
            const float4 b4 = *(const float4*)&Sj[jl + 8 * u][h0];
            e[u] = fmaf(fmaxf(a4.x + b4.x, 0.f), w0v, e[u]);
            e[u] = fmaf(fmaxf(a4.y + b4.y, 0.f), w1v, e[u]);
            e[u] = fmaf(fmaxf(a4.z + b4.z, 0.f), w2v, e[u]);
            e[u] = fmaf(fmaxf(a4.w + b4.w, 0.f), w3v, e[u]);
        }
    }

    const float a2bv = a2b[0];
    const long rowbase = ((long)(b * N_ + i0 + i)) * N_ + j0 + jl;
    float lsum = 0.f;
    #pragma unroll
    for (int u = 0; u < 4; ++u) {
        float ev = e[u] + a2bv;
        ev = (ev >= 0.f) ? ev : SLOPE_ * ev;
        const float m  = adj[rowbase + 8 * u];
        const float pv = m * __expf(ev);
        p[rowbase + 8 * u] = pv;
        lsum += pv;
    }

    #pragma unroll
    for (int off = 32; off > 0; off >>= 1)
        lsum += __shfl_down(lsum, off, 64);
    if ((t & 63) == 0) red[t >> 6] = lsum;
    __syncthreads();
    if (t == 0)
        Zpart[b * 256 + tile] = red[0] + red[1] + red[2] + red[3];
}

// ---------------------------------------------------------------------------
// Finalize: out = sum of 4 pre-scaled slices. 300 blocks x 256 threads,
// one float4 each (76800 total; rows of 300 floats = 75 float4, no straddle).
// ---------------------------------------------------------------------------
__global__ __launch_bounds__(256)
void finalize(const float4* __restrict__ slc, float4* __restrict__ out)
{
    const int idx = blockIdx.x * 256 + threadIdx.x;   // < 76800
    out[idx] = f4add(f4add(slc[idx],           slc[idx + 76800]),
                     f4add(slc[idx + 153600],  slc[idx + 230400]));
}

} // namespace

extern "C" void kernel_launch(void* const* d_in, const int* in_sizes, int n_in,
                              void* d_out, int out_size, void* d_ws, size_t ws_size,
                              hipStream_t stream)
{
    (void)in_sizes; (void)n_in; (void)out_size; (void)ws_size;
    const float* feature = (const float*)d_in[0];
    const float* adj     = (const float*)d_in[1];
    const float* w0      = (const float*)d_in[2];
    const float* b0      = (const float*)d_in[3];
    const float* w1      = (const float*)d_in[4];
    const float* b1      = (const float*)d_in[5];
    const float* a1w     = (const float*)d_in[6];   // (600, 64) row-major
    const float* a1b     = (const float*)d_in[7];
    const float* a2w     = (const float*)d_in[8];
    const float* a2b     = (const float*)d_in[9];
    float* out = (float*)d_out;
    float* ws  = (float*)d_ws;

    float* cW1Ai = ws + OFF_CW1AI;
    float* cW1Aj = ws + OFF_CW1AJ;
    float* bs1i  = ws + OFF_BS1I;
    float* bs1j  = ws + OFF_BS1J;
    float* h0s   = ws + OFF_H0S;    // 3 slices (split-K of h0)
    float* si0s  = ws + OFF_SI0S;   // 4 slices
    float* sj0s  = ws + OFF_SJ0S;   // 4 slices
    float* f1s   = ws + OFF_F1S;    // 4 slices (each scaled by 1/Z0)
    float* h1s   = ws + OFF_H1S;    // 2 slices
    float* si1s  = ws + OFF_SI1S;   // 2 slices
    float* sj1s  = ws + OFF_SJ1S;   // 2 slices
    float* Zp0   = ws + OFF_ZP0;
    float* Zp1   = ws + OFF_ZP1;
    float* p0    = ws + OFF_P0;
    float* p1    = ws + OFF_P1;
    float* outs  = ws + OFF_OUTS;   // 4 slices (each scaled by 1/Z1)

    const float* Ai = a1w;                    // top half (300 x 64)
    const float* Aj = a1w + (long)M_ * H_;    // bottom half

    auto set_job = [](JobsK& jb, int j, const float* A, long afs,
                      const float* W, long wfs, const float* bias,
                      const float* Zp, float* C, long cslice,
                      int K, int lda, int Cc, int R, int split, int& tiles) {
        jb.A[j] = A; jb.afs[j] = afs;
        jb.W[j] = W; jb.wfs[j] = wfs;
        jb.bias[j] = bias; jb.Zp[j] = Zp;
        jb.C[j] = C; jb.cslice[j] = cslice;
        jb.K[j] = K; jb.lda[j] = lda; jb.Cc[j] = Cc; jb.R[j] = R;
        jb.split[j] = split;
        jb.off[j] = tiles;
        tiles += ((R + 63) / 64) * ((Cc + 63) / 64) * split;
    };

    // ---- D1: h0 slices (split 3) + layer-1 fused weights (252 blocks) ----
    {
        JobsK jb; int tiles = 0;
        set_job(jb, 0, feature, 0, w0, 0, b0, nullptr, h0s, 307200,
                512, 512, M_, 1024, 3, tiles);                       // 240
        set_job(jb, 1, w1, 0, Ai, 0, nullptr, nullptr, cW1Ai, 0,
                M_, M_, H_, M_, 1, tiles);                           // 5
        set_job(jb, 2, w1, 0, Aj, 0, nullptr, nullptr, cW1Aj, 0,
                M_, M_, H_, M_, 1, tiles);                           // 5
        set_job(jb, 3, b1, 0, Ai, 0, nullptr, nullptr, bs1i, 0,
                M_, M_, H_, 1, 1, tiles);                            // 1
        set_job(jb, 4, b1, 0, Aj, 0, a1b, nullptr, bs1j, 0,
                M_, M_, H_, 1, 1, tiles);                            // 1
        jb.njobs = 5;
        gemm_jobs<1, 1><<<dim3(tiles), dim3(256), 0, stream>>>(jb);
    }

    // ---- D2: si0/sj0 slices = (fold-3 h0s)@{Ai,Aj}, split 4 (128) ----
    {
        JobsK jb; int tiles = 0;
        set_job(jb, 0, h0s, 307200, Ai, 0, nullptr, nullptr, si0s, 65536,
                M_, M_, H_, 1024, 4, tiles);                         // 64
        set_job(jb, 1, h0s, 307200, Aj, 0, a1b, nullptr, sj0s, 65536,
                M_, M_, H_, 1024, 4, tiles);                         // 64
        jb.njobs = 2;
        gemm_jobs<3, 1><<<dim3(tiles), dim3(256), 0, stream>>>(jb);
    }

    // ---- D3: attn0 (fold 4) -> p0, Zp0 (512 blocks) ----
    attn_k<4><<<dim3(512), dim3(256), 0, stream>>>(
        si0s, sj0s, adj, a2w, a2b, p0, Zp0);

    // ---- D4: f1 slices (split 4) = (1/Z0)*p0@(Wfold-3 h0s) (320) ----
    {
        JobsK jb; int tiles = 0;
        set_job(jb, 0, p0, 0, h0s, 307200, nullptr, Zp0, f1s, 307200,
                512, 512, M_, 512, 4, tiles);                        // 160
        set_job(jb, 1, p0 + 262144, 0, h0s + 153600, 307200, nullptr,
                Zp0 + 256, f1s + 153600, 307200,
                512, 512, M_, 512, 4, tiles);                        // 160
        jb.njobs = 2;
        gemm_jobs<1, 3><<<dim3(tiles), dim3(256), 0, stream>>>(jb);
    }

    // ---- D5: h1/si1/sj1 slices = (fold-4 f1s)@{w1,cW1Ai,cW1Aj} (224) ----
    {
        JobsK jb; int tiles = 0;
        set_job(jb, 0, f1s, 307200, w1, 0, b1, nullptr, h1s, 307200,
                M_, M_, M_, 1024, 2, tiles);                         // 160
        set_job(jb, 1, f1s, 307200, cW1Ai, 0, bs1i, nullptr, si1s, 65536,
                M_, M_, H_, 1024, 2, tiles);                         // 32
        set_job(jb, 2, f1s, 307200, cW1Aj, 0, bs1j, nullptr, sj1s, 65536,
                M_, M_, H_, 1024, 2, tiles);                         // 32
        jb.njobs = 3;
        gemm_jobs<4, 1><<<dim3(tiles), dim3(256), 0, stream>>>(jb);
    }

    // ---- D6: attn1 (fold 2) -> p1, Zp1 (512 blocks) ----
    attn_k<2><<<dim3(512), dim3(256), 0, stream>>>(
        si1s, sj1s, adj, a2w, a2b, p1, Zp1);

    // ---- D7: out slices (split 4) = (1/Z1)*p1@(Wfold-2 h1s) (320) ----
    {
        JobsK jb; int tiles = 0;
        set_job(jb, 0, p1, 0, h1s, 307200, nullptr, Zp1, outs, 307200,
                512, 512, M_, 512, 4, tiles);                        // 160
        set_job(jb, 1, p1 + 262144, 0, h1s + 153600, 307200, nullptr,
                Zp1 + 256, outs + 153600, 307200,
                512, 512, M_, 512, 4, tiles);                        // 160
        jb.njobs = 2;
        gemm_jobs<1, 2><<<dim3(tiles), dim3(256), 0, stream>>>(jb);
    }

    // ---- D8: out = sum of 4 pre-scaled slices (300 blocks) ----
    finalize<<<dim3(300), dim3(256), 0, stream>>>(
        (const float4*)outs, (float4*)out);
}